// Round 8
// baseline (182.530 us; speedup 1.0000x reference)
//
#include <hip/hip_runtime.h>

// STDP delta_w on MI355X, bf16-MFMA formulation (2-dispatch).
//   term1: dW1[o,p] = sum_k O[k,o]*TP[k,p], K = T*B = 1024  -> bf16 MFMA GEMM
//   term2: -coef[o]*W[o,p], coef[o] = sum_k O[k,o]*PO[k,o]  -> fp32 epilogue
//
// R14: R13 (best, 180.65us) with ONE change: MFMA shape 16x16x32 -> 32x32x16.
//   Matrix pipe: 2495 vs 2075 TF ubench (-17% MFMA cycles), half the MFMA
//   issues (8/phase vs 16). LDS traffic/bytes, staging ledger, barriers,
//   vmcnt modes, swizzle: IDENTICAL to the verified R9 skeleton.
//   Per phase: af[2 mt][2 ks], bv[2 nt][2 ks] (B reused across mqc as before),
//   8x mfma_f32_32x32x16_bf16 into acc[mqc][mt][nt] (f32x16).
//   C/D layout (m74/m101 verified): col=lane&31, row=(reg&3)+8*(reg>>2)+4*(lane>>5).
// Converter identical to R4 (passed repeatedly).
//
// ws: AT bf16 [4096][1024] (8MB) | BT bf16 [4096][1024] (8MB) | coef f32[4096]

#define T_STEPS 64
#define B_SZ    16
#define PRE     4096
#define POST    4096
#define K_TOT   1024

typedef __attribute__((ext_vector_type(8))) unsigned short ushort8;
typedef __attribute__((ext_vector_type(8))) __bf16 bf16x8;
typedef __attribute__((ext_vector_type(4))) float floatx4;
typedef __attribute__((ext_vector_type(16))) float floatx16;

__device__ __forceinline__ unsigned short f2bf(float f) {
    unsigned int u = __float_as_uint(f);
    u += 0x7fff + ((u >> 16) & 1);          // round-to-nearest-even
    return (unsigned short)(u >> 16);
}

__device__ __forceinline__ void glds16(const void* g, void* l) {
    __builtin_amdgcn_global_load_lds((const __attribute__((address_space(1))) void*)g,
                                     (__attribute__((address_space(3))) void*)l,
                                     16, 0, 0);
}

// ---------------------------------------------------------------------------
// Converter: grid = 256 blocks (matrix = blk>>7, p-chunk = blk&127), 256 thr.
// (verbatim R4 — passed repeatedly)
__global__ __launch_bounds__(256) void trace_convert(
        const float* __restrict__ in_spikes,
        const float* __restrict__ out_spikes,
        unsigned short* __restrict__ AT,
        unsigned short* __restrict__ BT,
        float* __restrict__ coef) {
    __shared__ float ldsf[4096];             // [8 t][16 b][32 p] fp32, 16 KB
    __shared__ unsigned short ot[128 * 34];  // [128 k][32 p + 2 pad], 8.5 KB
    __shared__ float cbuf[8][33];
    const int tid  = threadIdx.x;
    const int wave = tid >> 6;
    const int lane = tid & 63;
    const bool isA = blockIdx.x >= 128;
    const int p0 = (blockIdx.x & 127) * 32;
    const float* src = isA ? out_spikes : in_spikes;
    unsigned short* dst = isA ? AT : BT;

    const int bA = tid >> 5;                 // chains (bA, p) and (bA+8, p)
    const int pA = tid & 31;

    float st0 = 0.f, st1 = 0.f, c0 = 0.f, c1 = 0.f;

    for (int tc = 0; tc < 8; ++tc) {
        const int T0 = tc * 8;
        // ---- stage 16 b x 8 t x 32 p fp32 into LDS (4 glds x16B per wave)
        #pragma unroll
        for (int i = 0; i < 4; ++i) {
            const int q  = (wave * 4 + i) * 64 + lane;  // float-quad id 0..1023
            const int p  = (q & 7) * 4;
            const int b  = (q >> 3) & 15;
            const int tl = q >> 7;
            const float* g = src + ((size_t)((T0 + tl) * 16 + b)) * 4096 + p0 + p;
            glds16(g, (char*)ldsf + (size_t)(wave * 4 + i) * 1024);
        }
        __syncthreads();                     // drains vmcnt

        // ---- recurrence: 8 t-steps, 2 chains per thread
        #pragma unroll
        for (int tl = 0; tl < 8; ++tl) {
            const float x0 = ldsf[tl * 512 + bA * 32 + pA];
            const float x1 = ldsf[tl * 512 + (bA + 8) * 32 + pA];
            if (isA) {
                st0 = 0.5f * st0 + x0; c0 += x0 * st0;   // po update, then o*po
                st1 = 0.5f * st1 + x1; c1 += x1 * st1;
                ot[(tl * 16 + bA)     * 34 + pA] = f2bf(x0);
                ot[(tl * 16 + bA + 8) * 34 + pA] = f2bf(x1);
            } else {
                st0 = fminf(fmaxf(0.5f * st0 + x0, 0.f), 1.f);
                st1 = fminf(fmaxf(0.5f * st1 + x1, 0.f), 1.f);
                ot[(tl * 16 + bA)     * 34 + pA] = f2bf(st0);
                ot[(tl * 16 + bA + 8) * 34 + pA] = f2bf(st1);
            }
        }
        __syncthreads();

        // ---- flush: 128 contiguous k per p-row, 16-B vector stores
        const int pf = tid >> 3;             // 0..31
        const int c8 = tid & 7;
        #pragma unroll
        for (int i = 0; i < 2; ++i) {
            const int ch = c8 + i * 8;       // 16-B chunk 0..15
            ushort8 v;
            #pragma unroll
            for (int s = 0; s < 8; ++s) v[s] = ot[(ch * 8 + s) * 34 + pf];
            *(ushort8*)&dst[(size_t)(p0 + pf) * K_TOT + T0 * 16 + ch * 8] = v;
        }
    }

    if (isA) {
        cbuf[bA][pA] = c0 + c1;              // partial over b in {bA, bA+8}
        __syncthreads();
        if (tid < 32) {
            float s = 0.f;
            #pragma unroll
            for (int r = 0; r < 8; ++r) s += cbuf[r][tid];
            coef[p0 + tid] = s;
        }
    }
}

// ---------------------------------------------------------------------------
// 8-phase GEMM, R9 skeleton, 32x32x16 MFMA.
#define NTILES 16
#define LOFF(buf, isB, kh) ((buf) * 65536 + (isB) * 32768 + (kh) * 16384)

__global__ __launch_bounds__(512, 2) void stdp_gemm_mfma(
        const unsigned short* __restrict__ AT,   // [POST][K] bf16 bits
        const unsigned short* __restrict__ BT,   // [PRE][K]  bf16 bits
        const float* __restrict__ W,             // [POST][PRE]
        const float* __restrict__ coef,          // [POST]
        float* __restrict__ Cout) {              // [POST][PRE]
    __shared__ __align__(16) char ldsraw[131072];   // 128 KB -> 1 block/CU

    const int tid  = threadIdx.x;
    const int lane = tid & 63;
    const int wave = tid >> 6;

    // XCD-bijective swizzle: 256 blocks = 8 XCD x 32; each XCD: 2 m-panels x 16 n.
    const int bid = blockIdx.x;
    const int f   = (bid & 7) * 32 + (bid >> 3);
    const int m0  = (f >> 4) * 256;
    const int n0  = (f & 15) * 256;

    const int wm  = (wave >> 2) * 128;           // 2 M-groups (rows within tile)
    const int wn  = (wave & 3) * 64;             // 4 N-groups
    const int l31 = lane & 31;                   // fragment row within 32
    const int lh  = lane >> 5;                   // k-halfgroup (8 k) within 16-k span
    const int swA = (l31 >> 1) & 3;              // read-side chunk swizzle (row bits 1-2)

    floatx16 acc[2][2][2];                       // [mqc][mt][nt], all static-indexed
    #pragma unroll
    for (int i = 0; i < 2; ++i)
        #pragma unroll
        for (int j = 0; j < 2; ++j)
            #pragma unroll
            for (int k = 0; k < 2; ++k)
                acc[i][j][k] = (floatx16){0.f,0.f,0.f,0.f,0.f,0.f,0.f,0.f,
                                          0.f,0.f,0.f,0.f,0.f,0.f,0.f,0.f};
    bf16x8 bv[2][2];                             // [nt][ks], live across phase pairs

    // Staging map (verbatim R9): chunkID cid = wave*64 + lane; row = cid>>2
    // (j=0: 0..127, j=1: +128), slot cid&3 receives global chunk slot^((row>>1)&3).
    const int cid0 = wave * 64 + lane;
    const int row0 = cid0 >> 2;
    const int g0   = (cid0 & 3) ^ ((row0 >> 1) & 3);
    const unsigned short* gA0 = AT + (size_t)(m0 + row0) * K_TOT + g0 * 8;
    const unsigned short* gB0 = BT + (size_t)(n0 + row0) * K_TOT + g0 * 8;

    #define STG(isB, t, kh)                                                        \
        do {                                                                       \
            const unsigned short* s0_ = ((isB) ? gB0 : gA0) + (t) * 64 + (kh) * 32;\
            char* d_ = ldsraw + LOFF((t) & 1, (isB), (kh)) + wave * 1024;          \
            glds16(s0_, d_);                                                       \
            glds16(s0_ + (size_t)128 * K_TOT, d_ + 8192);                          \
        } while (0)

    // Phase: quadrant (bufc, khc, mqc) = 64 m x 64 n x 32 k, as 2x2x2 32x32x16.
    // Global k-chunk c of row r sits at LDS slot c^((r>>1)&3); here
    // (r>>1)&3 == swA since all row bases are multiples of 32.
    #define PHASE(bufc, khc, mqc, SISB, ST, SKH, SCOND, WM)                        \
        do {                                                                       \
            const char* Ab_ = ldsraw + LOFF(bufc, 0, khc);                         \
            const char* Bb_ = ldsraw + LOFF(bufc, 1, khc);                         \
            if ((mqc) == 0) {                                                      \
                _Pragma("unroll")                                                  \
                for (int nt = 0; nt < 2; ++nt)                                     \
                    _Pragma("unroll")                                              \
                    for (int ks = 0; ks < 2; ++ks)                                 \
                        bv[nt][ks] = *(const bf16x8*)(Bb_                          \
                            + (wn + nt * 32 + l31) * 64                            \
                            + (((ks * 2 + lh) ^ swA) << 4));                       \
            }                                                                      \
            bf16x8 af_[2][2];                                                      \
            _Pragma("unroll")                                                      \
            for (int mt = 0; mt < 2; ++mt)                                         \
                _Pragma("unroll")                                                  \
                for (int ks = 0; ks < 2; ++ks)                                     \
                    af_[mt][ks] = *(const bf16x8*)(Ab_                             \
                        + (wm + (mqc) * 64 + mt * 32 + l31) * 64                   \
                        + (((ks * 2 + lh) ^ swA) << 4));                           \
            if (SCOND) STG(SISB, ST, SKH);                                         \
            if ((WM) == 1)      asm volatile("s_waitcnt vmcnt(4)" ::: "memory");   \
            else if ((WM) == 2) asm volatile("s_waitcnt vmcnt(0)" ::: "memory");   \
            __builtin_amdgcn_s_barrier();                                          \
            __builtin_amdgcn_sched_barrier(0);                                     \
            __builtin_amdgcn_s_setprio(1);                                         \
            _Pragma("unroll")                                                      \
            for (int mt = 0; mt < 2; ++mt)                                         \
                _Pragma("unroll")                                                  \
                for (int nt = 0; nt < 2; ++nt)                                     \
                    _Pragma("unroll")                                              \
                    for (int ks = 0; ks < 2; ++ks)                                 \
                        acc[mqc][mt][nt] = __builtin_amdgcn_mfma_f32_32x32x16_bf16(\
                            af_[mt][ks], bv[nt][ks], acc[mqc][mt][nt], 0, 0, 0);   \
            __builtin_amdgcn_s_setprio(0);                                         \
            __builtin_amdgcn_s_barrier();                                          \
            __builtin_amdgcn_sched_barrier(0);                                     \
        } while (0)

    STG(0, 0, 0); STG(1, 0, 0); STG(0, 0, 1); STG(1, 0, 1);
    STG(0, 1, 0); STG(1, 1, 0); STG(0, 1, 1); STG(1, 1, 1);
    asm volatile("s_waitcnt vmcnt(8)" ::: "memory");
    __builtin_amdgcn_s_barrier();
    __builtin_amdgcn_sched_barrier(0);

    for (int i = 0; i < 8; ++i) {
        const int t2 = 2 * i + 2, t3 = 2 * i + 3, tA = 2 * i + 1;
        const int wm4 = (i < 7) ? 1 : 2;         // ph4 wait: publish buf1
        const int wm8 = (i < 7) ? 1 : 0;         // ph8 wait: publish buf0 (none at end)
        PHASE(0, 0, 0, 0, tA, 1, i > 0,      0);     // ph1
        PHASE(0, 0, 1, 1, tA, 1, i > 0,      0);     // ph2
        PHASE(0, 1, 0, 0, t2, 0, t2 < NTILES, 0);    // ph3
        PHASE(0, 1, 1, 1, t2, 0, t2 < NTILES, wm4);  // ph4
        PHASE(1, 0, 0, 0, t2, 1, t2 < NTILES, 0);    // ph5
        PHASE(1, 0, 1, 1, t2, 1, t2 < NTILES, 0);    // ph6
        PHASE(1, 1, 0, 0, t3, 0, t3 < NTILES, 0);    // ph7
        PHASE(1, 1, 1, 1, t3, 0, t3 < NTILES, wm8);  // ph8
    }

    // Epilogue: C = acc - coef[o]*W.
    // 32x32 C/D layout (m74/m101): col = lane&31, row = (reg&3)+8*(reg>>2)+4*(lane>>5).
    #pragma unroll
    for (int mqc = 0; mqc < 2; ++mqc) {
        #pragma unroll
        for (int mt = 0; mt < 2; ++mt) {
            #pragma unroll
            for (int nt = 0; nt < 2; ++nt) {
                const int R0  = m0 + wm + mqc * 64 + mt * 32;
                const int col = n0 + wn + nt * 32 + l31;
                #pragma unroll
                for (int reg = 0; reg < 16; ++reg) {
                    const int row = R0 + (reg & 3) + 8 * (reg >> 2) + 4 * lh;
                    const float cf = coef[row];
                    const float wv = W[(size_t)row * PRE + col];
                    Cout[(size_t)row * PRE + col] = acc[mqc][mt][nt][reg] - cf * wv;
                }
            }
        }
    }
    #undef PHASE
    #undef STG
}

// ---------------------------------------------------------------------------
extern "C" void kernel_launch(void* const* d_in, const int* in_sizes, int n_in,
                              void* d_out, int out_size, void* d_ws, size_t ws_size,
                              hipStream_t stream) {
    const float* in_spikes  = (const float*)d_in[0];
    const float* out_spikes = (const float*)d_in[1];
    const float* weight     = (const float*)d_in[2];
    float* out = (float*)d_out;

    unsigned short* AT = (unsigned short*)d_ws;                 // 8 MB
    unsigned short* BT = AT + (size_t)POST * K_TOT;             // 8 MB
    float* coef = (float*)(BT + (size_t)PRE * K_TOT);           // 16 KB

    trace_convert<<<256, 256, 0, stream>>>(in_spikes, out_spikes, AT, BT, coef);

    stdp_gemm_mfma<<<256, 512, 0, stream>>>(AT, BT, weight, coef, out);
}